// Round 14
// baseline (613.961 us; speedup 1.0000x reference)
//
#include <hip/hip_runtime.h>
#include <hip/hip_bf16.h>
#include <stdint.h>

// Problem constants (MixtralAttention: B=2, S=2048, H=4096, 32 q-heads, 8 kv-heads, HD=128)
#define Hdim 4096
#define NH 32
#define NKV 8
#define HDs 128
#define Bb 2
#define Ss 2048
#define QKV_N 6144              // NH*HD + 2*NKV*HD
#define SCALEF 0.08838834764831845f   // 128^-0.5
#define LOG2E 1.4426950408889634f
// sliding window = 4096 >= S=2048  ->  pure causal mask

typedef __attribute__((ext_vector_type(4))) float f32x4;
typedef __attribute__((ext_vector_type(16))) float f32x16;
typedef __attribute__((ext_vector_type(8))) short bf16x8;

__device__ __forceinline__ unsigned short f2bf(float f) {
  union { float f; unsigned u; } v; v.f = f;
  unsigned r = v.u + 0x7fffu + ((v.u >> 16) & 1u);   // RNE
  return (unsigned short)(r >> 16);
}
__device__ __forceinline__ float bf2f(unsigned short h) {
  union { unsigned u; float f; } v; v.u = ((unsigned)h) << 16;
  return v.f;
}
__device__ __forceinline__ unsigned cvtpk(float lo, float hi) {
  unsigned r;
  asm("v_cvt_pk_bf16_f32 %0, %1, %2" : "=v"(r) : "v"(lo), "v"(hi));
  return r;
}

#define GLOBAL_AS(p) ((const __attribute__((address_space(1))) void*)(p))
#define LDS_AS(p)    ((__attribute__((address_space(3))) void*)(p))

// ---------------- k_pre: hidden fp32->bf16  +  wqkv transpose (merged) ----------------
__global__ void k_pre(const float* __restrict__ hidden, unsigned short* __restrict__ hbf,
                      const float* __restrict__ wqkv, unsigned short* __restrict__ wT) {
  __shared__ unsigned short tile[32][33];
  int bid = blockIdx.x;
  int t = threadIdx.x;
  if (bid < 16384) {
    int i = (bid * 256 + t) * 4;
    f32x4 v = *(const f32x4*)(hidden + i);
    uint2 o;
    o.x = (unsigned)f2bf(v.x) | ((unsigned)f2bf(v.y) << 16);
    o.y = (unsigned)f2bf(v.z) | ((unsigned)f2bf(v.w) << 16);
    *(uint2*)(hbf + i) = o;
  } else {
    int idx = bid - 16384;                 // 192 n-tiles x 128 k-tiles
    int n0 = (idx % 192) * 32, k0 = (idx / 192) * 32;
    int tx = t & 31, ty0 = t >> 5;
#pragma unroll
    for (int i = 0; i < 4; i++) {
      int ty = ty0 + i * 8;
      tile[ty][tx] = f2bf(wqkv[(size_t)(k0 + ty) * QKV_N + n0 + tx]);
    }
    __syncthreads();
#pragma unroll
    for (int i = 0; i < 4; i++) {
      int ty = ty0 + i * 8;
      wT[(size_t)(n0 + ty) * Hdim + k0 + tx] = tile[tx][ty];
    }
  }
}

// ---------------- k_mid: RoPE + V^T repack + wo transpose (merged, all post-GEMM1) ----
__global__ void k_mid(unsigned short* __restrict__ qkv, const int* __restrict__ pos,
                      unsigned short* __restrict__ vt,
                      const float* __restrict__ wo, unsigned short* __restrict__ wT) {
  __shared__ unsigned short tile[32][33];
  int bid = blockIdx.x;
  int t = threadIdx.x;
  if (bid < 40960) {
    int x = bid % 10;
    int bs = bid / 10;                     // b*S + s
    int head = x * 4 + (t >> 6);           // 0..39 (0-31 q, 32-39 k)
    int p = t & 63;                        // pair index
    int col;
    float scale;
    if (head < NH) { col = head * HDs + 2 * p; scale = SCALEF * LOG2E; }
    else           { col = NH * HDs + (head - NH) * HDs + 2 * p; scale = 1.f; }
    size_t idx = (size_t)bs * QKV_N + col;
    float x0 = bf2f(qkv[idx]), x1 = bf2f(qkv[idx + 1]);
    float position = (float)pos[bs];
    float inv_freq = exp2f((float)p * -0.2076205059304601f);
    float ang = position * inv_freq;
    float sv, cv;
    sincosf(ang, &sv, &cv);
    qkv[idx]     = f2bf((x0 * cv - x1 * sv) * scale);
    qkv[idx + 1] = f2bf((x1 * cv + x0 * sv) * scale);
  } else if (bid < 45056) {
    int idx = bid - 40960;
    int bkv = idx >> 8;                    // b*NKV + kvh
    int d0 = ((idx >> 6) & 3) * 32;
    int s0 = (idx & 63) * 32;
    int b = bkv >> 3, kvh = bkv & 7;
    int tx = t & 31, ty0 = t >> 5;
    const unsigned short* src = qkv + (size_t)b * Ss * QKV_N + NH * HDs + NKV * HDs + kvh * HDs;
#pragma unroll
    for (int i = 0; i < 4; i++) {
      int ty = ty0 + i * 8;
      tile[ty][tx] = src[(size_t)(s0 + ty) * QKV_N + d0 + tx];
    }
    __syncthreads();
    unsigned short* dst = vt + (size_t)bkv * HDs * Ss;
    int c = s0 + tx;
    int o = c & 63;
    int pcol = (c & ~63) | ((o & 32) | ((o & 12) << 1) | ((o & 16) >> 2) | (o & 3));
#pragma unroll
    for (int i = 0; i < 4; i++) {
      int ty = ty0 + i * 8;
      dst[(size_t)(d0 + ty) * Ss + pcol] = tile[tx][ty];
    }
  } else {
    int idx = bid - 45056;                 // 128 x 128 tiles
    int n0 = (idx % 128) * 32, k0 = (idx / 128) * 32;
    int tx = t & 31, ty0 = t >> 5;
#pragma unroll
    for (int i = 0; i < 4; i++) {
      int ty = ty0 + i * 8;
      tile[ty][tx] = f2bf(wo[(size_t)(k0 + ty) * Hdim + n0 + tx]);
    }
    __syncthreads();
#pragma unroll
    for (int i = 0; i < 4; i++) {
      int ty = ty0 + i * 8;
      wT[(size_t)(n0 + ty) * Hdim + k0 + tx] = tile[tx][ty];
    }
  }
}

// ---------------- bf16 GEMM, r7 structure, 32x32x16 MFMA (r14 change) -----------------
// Same staging/swizzle/counted-vmcnt/barriers as r7 (37% plateau best).  Only the MFMA
// shape changes: wave tile 64x64 = 2x2 frags of 32x32x16 (ubench 2382 vs 2075 TF; half
// the MFMA instruction count and waitcnt boundaries per FLOP; LDS bytes/FLOP identical).
// Operand layout: row/col = lane&31, k = (lane>>5)*8+e.  C/D: col=lane&31,
// row=(reg&3)+8*(reg>>2)+4*(lane>>5), reg in [0,16)  [verified m74/m101].
template <int OUT_BF16>
__global__ __launch_bounds__(512) void k_gemm8(const unsigned short* __restrict__ A,
                                               const unsigned short* __restrict__ Bt,
                                               void* __restrict__ C,
                                               int M, int N, int K, int nbn) {
  __shared__ __align__(16) unsigned short As[3][256 * 64];   // 96 KB
  __shared__ __align__(16) unsigned short Bs[3][128 * 64];   // 48 KB

  int nwg = gridDim.x;
  int orig = blockIdx.x;
  int wg = (orig & 7) * (nwg >> 3) + (orig >> 3);
  int bm = wg / nbn, bn = wg % nbn;

  int t = threadIdx.x, w = t >> 6, lane = t & 63;
  int wm = w >> 1, wn = w & 1;
  int l31 = lane & 31, l5 = lane >> 5;

  const unsigned short* Ag = A + (size_t)(bm * 256) * K;
  const unsigned short* Bg = Bt + (size_t)(bn * 128) * K;

  int srow = w * 8 + (lane >> 3);
  int sloff = ((lane & 7) ^ ((lane >> 3) & 7)) * 8;

  f32x16 acc[2][2];
#pragma unroll
  for (int m = 0; m < 2; m++)
#pragma unroll
    for (int n = 0; n < 2; n++)
#pragma unroll
      for (int r = 0; r < 16; r++) acc[m][n][r] = 0.f;

  int NKT = K >> 6;

  auto stage_half = [&](int buf, int kt, int h) {
#pragma unroll
    for (int i2 = 0; i2 < 2; i2++) {
      int row = h * 128 + i2 * 64 + srow;
      __builtin_amdgcn_global_load_lds(GLOBAL_AS(Ag + (size_t)row * K + kt * 64 + sloff),
                                       LDS_AS(&As[buf][h * 8192 + i2 * 4096 + w * 512]), 16, 0, 0);
    }
    {
      int row = h * 64 + srow;
      __builtin_amdgcn_global_load_lds(GLOBAL_AS(Bg + (size_t)row * K + kt * 64 + sloff),
                                       LDS_AS(&Bs[buf][h * 4096 + w * 512]), 16, 0, 0);
    }
  };

  stage_half(0, 0, 0); stage_half(0, 0, 1);
  stage_half(1, 1, 0); stage_half(1, 1, 1);
  asm volatile("s_waitcnt vmcnt(6)" ::: "memory");
  __builtin_amdgcn_s_barrier();

  for (int kt = 0; kt < NKT; kt++) {
    int cb = kt % 3;
    const unsigned short* Abp = As[cb];
    const unsigned short* Bbp = Bs[cb];
#pragma unroll
    for (int q = 0; q < 2; q++) {
      // half q covers ksteps ks = q*2+j (j=0,1), each K=16 (2x 16B slots)
      bf16x8 af[2][2], bf[2][2];     // [j][mi] / [j][ni]
#pragma unroll
      for (int j = 0; j < 2; j++) {
        int ks = q * 2 + j;
        int slot = ks * 2 + l5;      // logical 16B slot
#pragma unroll
        for (int mi = 0; mi < 2; mi++) {
          int row = wm * 64 + mi * 32 + l31;
          af[j][mi] = *(const bf16x8*)&Abp[row * 64 + ((slot ^ (row & 7)) << 3)];
        }
#pragma unroll
        for (int ni = 0; ni < 2; ni++) {
          int row = wn * 64 + ni * 32 + l31;
          bf[j][ni] = *(const bf16x8*)&Bbp[row * 64 + ((slot ^ (row & 7)) << 3)];
        }
      }
      if (kt + 2 < NKT) stage_half((kt + 2) % 3, kt + 2, q);
      __builtin_amdgcn_s_barrier();
      asm volatile("s_waitcnt lgkmcnt(0)" ::: "memory");
      __builtin_amdgcn_s_setprio(1);
#pragma unroll
      for (int j = 0; j < 2; j++)
#pragma unroll
        for (int mi = 0; mi < 2; mi++)
#pragma unroll
          for (int ni = 0; ni < 2; ni++)
            acc[mi][ni] = __builtin_amdgcn_mfma_f32_32x32x16_bf16(af[j][mi], bf[j][ni],
                                                                  acc[mi][ni], 0, 0, 0);
      __builtin_amdgcn_s_setprio(0);
      if (q == 1) {
        if (kt + 2 < NKT) asm volatile("s_waitcnt vmcnt(6)" ::: "memory");
        else              asm volatile("s_waitcnt vmcnt(0)" ::: "memory");
      }
      __builtin_amdgcn_s_barrier();
    }
  }

  // epilogue: C/D layout col=lane&31, row=(reg&3)+8*(reg>>2)+4*(lane>>5)  [m74/m101]
#pragma unroll
  for (int mi = 0; mi < 2; mi++)
#pragma unroll
    for (int ni = 0; ni < 2; ni++) {
      int col = bn * 128 + wn * 64 + ni * 32 + l31;
#pragma unroll
      for (int r = 0; r < 16; r++) {
        int row = bm * 256 + wm * 64 + mi * 32 + (r & 3) + 8 * (r >> 2) + 4 * l5;
        float v = acc[mi][ni][r];
        if (OUT_BF16)
          ((unsigned short*)C)[(size_t)row * N + col] = f2bf(v);
        else
          ((float*)C)[(size_t)row * N + col] = v;
      }
    }
}

// ---------------- Flash attention v5b (r12, unchanged): 8 waves, true LPT ----------
__global__ __launch_bounds__(512, 4) void k_attn(const unsigned short* __restrict__ qkv,
                                                 const unsigned short* __restrict__ vt,
                                                 unsigned short* __restrict__ out) {
  __shared__ __align__(16) unsigned short Ks[2][64 * 128];   // 32 KB
  __shared__ __align__(16) unsigned short Vs[2][128 * 64];   // 32 KB

  int bid = blockIdx.x;
  int qc = 15 - (bid >> 6);     // true LPT: heavy q-chunks dispatched first
  int bh = bid & 63;
  int h = bh & 31;
  int b = bh >> 5;
  int kvh = h >> 2;             // GROUP = 4
  int t = threadIdx.x;
  int w = t >> 6, lane = t & 63;
  int l15 = lane & 15, l4 = lane >> 4;
  int qb0 = qc * 128;
  int qw = qb0 + w * 16;        // this wave's 16 q rows

  const unsigned short* kbase = qkv + (size_t)b * Ss * QKV_N + NH * HDs + (size_t)kvh * HDs;
  const unsigned short* vbase = vt + ((size_t)(b * NKV + kvh)) * HDs * Ss;

  bf16x8 qf[4];
#pragma unroll
  for (int ch = 0; ch < 4; ch++)
    qf[ch] = *(const bf16x8*)&qkv[((size_t)(b * Ss) + qw + l15) * QKV_N +
                                  (size_t)h * HDs + ch * 32 + l4 * 8];

  f32x4 zero = {0.f, 0.f, 0.f, 0.f};
  f32x4 acc[8];
#pragma unroll
  for (int dt = 0; dt < 8; dt++) acc[dt] = zero;
  float mrun = -1e30f, lsum = 0.f;

  int nkv = qc * 2 + 2;

  auto stageK = [&](int bufi, int kv_) {
#pragma unroll
    for (int i2 = 0; i2 < 2; i2++) {
      int row = i2 * 32 + (t >> 4);
      int sl = (t & 15) ^ (row & 7);
      __builtin_amdgcn_global_load_lds(GLOBAL_AS(kbase + (size_t)(kv_ + row) * QKV_N + sl * 8),
                                       LDS_AS(&Ks[bufi][i2 * 4096 + w * 512]), 16, 0, 0);
    }
  };
  auto stageV = [&](int bufi, int kv_) {
#pragma unroll
    for (int i2 = 0; i2 < 2; i2++) {
      int row = i2 * 64 + (t >> 3);
      int sl = (t & 7) ^ (row & 7);
      __builtin_amdgcn_global_load_lds(GLOBAL_AS(vbase + (size_t)row * Ss + kv_ + sl * 8),
                                       LDS_AS(&Vs[bufi][i2 * 4096 + w * 512]), 16, 0, 0);
    }
  };

  stageK(0, 0); stageV(0, 0);
  for (int it = 0; it < nkv; it++) {
    int kvb = it * 64;
    bool more = (it + 1 < nkv);
    if (more) {
      stageK((it + 1) & 1, kvb + 64);
      stageV((it + 1) & 1, kvb + 64);
      asm volatile("s_waitcnt vmcnt(4)" ::: "memory");
    } else {
      asm volatile("s_waitcnt vmcnt(0)" ::: "memory");
    }
    __builtin_amdgcn_s_barrier();

    if (kvb <= qw + 15) {
      const unsigned short* Kb = Ks[it & 1];
      const unsigned short* Vb = Vs[it & 1];

      f32x4 sacc[4];
#pragma unroll
      for (int kt2 = 0; kt2 < 4; kt2++) sacc[kt2] = zero;
#pragma unroll
      for (int kt2 = 0; kt2 < 4; kt2++) {
        int row = kt2 * 16 + l15;
#pragma unroll
        for (int ch = 0; ch < 4; ch++) {
          int ps = (ch * 4 + l4) ^ (row & 7);
          bf16x8 kf = *(const bf16x8*)&Kb[row * 128 + ps * 8];
          sacc[kt2] = __builtin_amdgcn_mfma_f32_16x16x32_bf16(kf, qf[ch], sacc[kt2], 0, 0, 0);
        }
      }

      int qi = qw + l15;
      bool fullvis = (kvb + 63 <= qw);
      float pv[16];
      float tmax = -1e30f;
#pragma unroll
      for (int kt2 = 0; kt2 < 4; kt2++)
#pragma unroll
        for (int r = 0; r < 4; r++) {
          int kvi = kvb + kt2 * 16 + l4 * 4 + r;
          float v = sacc[kt2][r];
          if (!fullvis) v = (kvi <= qi) ? v : -1e30f;
          pv[kt2 * 4 + r] = v;
          tmax = fmaxf(tmax, v);
        }
      tmax = fmaxf(tmax, __shfl_xor(tmax, 16));
      tmax = fmaxf(tmax, __shfl_xor(tmax, 32));
      if (!__all(tmax - mrun <= 8.f)) {
        float mnew = fmaxf(mrun, tmax);
        float fsc = exp2f(mrun - mnew);
        mrun = mnew;
        lsum *= fsc;
        float fr[4];
#pragma unroll
        for (int r = 0; r < 4; r++) fr[r] = __shfl(fsc, l4 * 4 + r);
#pragma unroll
        for (int dt = 0; dt < 8; dt++)
#pragma unroll
        for (int r = 0; r < 4; r++) acc[dt][r] *= fr[r];
      }
      float rs = 0.f;
#pragma unroll
      for (int i = 0; i < 16; i++) {
        pv[i] = exp2f(pv[i] - mrun);
        rs += pv[i];
      }
      rs += __shfl_xor(rs, 16);
      rs += __shfl_xor(rs, 32);
      lsum += rs;

      bf16x8 pa[2];
      {
        union { unsigned u[4]; bf16x8 v8; } pk0, pk1;
#pragma unroll
        for (int i = 0; i < 4; i++) pk0.u[i] = cvtpk(pv[2 * i], pv[2 * i + 1]);
#pragma unroll
        for (int i = 0; i < 4; i++) pk1.u[i] = cvtpk(pv[8 + 2 * i], pv[8 + 2 * i + 1]);
        pa[0] = pk0.v8;
        pa[1] = pk1.v8;
      }

#pragma unroll
      for (int kc = 0; kc < 2; kc++)
#pragma unroll
        for (int dt = 0; dt < 8; dt++) {
          int d = dt * 16 + l15;
          int ps = (kc * 4 + l4) ^ (d & 7);
          bf16x8 vf = *(const bf16x8*)&Vb[d * 64 + ps * 8];
          acc[dt] = __builtin_amdgcn_mfma_f32_16x16x32_bf16(pa[kc], vf, acc[dt], 0, 0, 0);
        }
    }
    asm volatile("s_waitcnt lgkmcnt(0)" ::: "memory");
    __builtin_amdgcn_s_barrier();
  }

  float lr[4];
#pragma unroll
  for (int r = 0; r < 4; r++) lr[r] = __shfl(lsum, l4 * 4 + r);
#pragma unroll
  for (int dt = 0; dt < 8; dt++)
#pragma unroll
    for (int r = 0; r < 4; r++) {
      int row = qw + l4 * 4 + r;
      out[((size_t)(b * Ss) + row) * Hdim + (size_t)h * HDs + dt * 16 + l15] =
          f2bf(acc[dt][r] / lr[r]);
    }
}

// ---------------- launcher ----------------
extern "C" void kernel_launch(void* const* d_in, const int* in_sizes, int n_in,
                              void* d_out, int out_size, void* d_ws, size_t ws_size,
                              hipStream_t stream) {
  const float* hidden = (const float*)d_in[0];
  const int* positions = (const int*)d_in[1];
  const float* wqkv = (const float*)d_in[2];
  const float* wo = (const float*)d_in[3];
  float* out = (float*)d_out;
  char* ws = (char*)d_ws;

  unsigned short* hbf  = (unsigned short*)(ws);
  unsigned short* wT   = (unsigned short*)(ws + 33554432);
  unsigned short* qkvb = (unsigned short*)(ws + 83886080);
  unsigned short* vtb  = (unsigned short*)(ws + 134217728);

  // 1. pre: hidden fp32->bf16 + wqkvT  (merged: 16384 + 24576 blocks)
  k_pre<<<40960, 256, 0, stream>>>(hidden, hbf, wqkv, wT);
  // 2. qkv = hidden @ wqkv   (bf16 out), grid 16x48 = 768 (%8==0)
  k_gemm8<1><<<(4096 / 256) * (QKV_N / 128), 512, 0, stream>>>(hbf, wT, qkvb, 4096, QKV_N, 4096, QKV_N / 128);
  // 3. mid: RoPE + V^T repack + woT  (merged: 40960 + 4096 + 16384 blocks)
  k_mid<<<61440, 256, 0, stream>>>(qkvb, positions, vtb, wo, wT);
  // 4. flash attention v5b -> attn_out (reuses ws0)
  k_attn<<<Bb * NH * (Ss / 128), 512, 0, stream>>>(qkvb, vtb, hbf);
  // 5. out = attn_out @ wo  (fp32 out), grid 16x32 = 512 (%8==0)
  k_gemm8<0><<<(4096 / 256) * (4096 / 128), 512, 0, stream>>>(hbf, wT, out, 4096, 4096, 4096, 4096 / 128);
}

// Round 15
// 568.497 us; speedup vs baseline: 1.0800x; 1.0800x over previous
//
#include <hip/hip_runtime.h>
#include <hip/hip_bf16.h>
#include <stdint.h>

// Problem constants (MixtralAttention: B=2, S=2048, H=4096, 32 q-heads, 8 kv-heads, HD=128)
#define Hdim 4096
#define NH 32
#define NKV 8
#define HDs 128
#define Bb 2
#define Ss 2048
#define QKV_N 6144              // NH*HD + 2*NKV*HD
#define SCALEF 0.08838834764831845f   // 128^-0.5
#define LOG2E 1.4426950408889634f
// sliding window = 4096 >= S=2048  ->  pure causal mask

typedef __attribute__((ext_vector_type(4))) float f32x4;
typedef __attribute__((ext_vector_type(8))) short bf16x8;

__device__ __forceinline__ unsigned short f2bf(float f) {
  union { float f; unsigned u; } v; v.f = f;
  unsigned r = v.u + 0x7fffu + ((v.u >> 16) & 1u);   // RNE
  return (unsigned short)(r >> 16);
}
__device__ __forceinline__ float bf2f(unsigned short h) {
  union { unsigned u; float f; } v; v.u = ((unsigned)h) << 16;
  return v.f;
}
__device__ __forceinline__ unsigned cvtpk(float lo, float hi) {
  unsigned r;
  asm("v_cvt_pk_bf16_f32 %0, %1, %2" : "=v"(r) : "v"(lo), "v"(hi));
  return r;
}

#define GLOBAL_AS(p) ((const __attribute__((address_space(1))) void*)(p))
#define LDS_AS(p)    ((__attribute__((address_space(3))) void*)(p))

// ---------------- k_pre: hidden fp32->bf16  +  wqkv transpose (merged) ----------------
__global__ void k_pre(const float* __restrict__ hidden, unsigned short* __restrict__ hbf,
                      const float* __restrict__ wqkv, unsigned short* __restrict__ wT) {
  __shared__ unsigned short tile[32][33];
  int bid = blockIdx.x;
  int t = threadIdx.x;
  if (bid < 16384) {
    int i = (bid * 256 + t) * 4;
    f32x4 v = *(const f32x4*)(hidden + i);
    uint2 o;
    o.x = (unsigned)f2bf(v.x) | ((unsigned)f2bf(v.y) << 16);
    o.y = (unsigned)f2bf(v.z) | ((unsigned)f2bf(v.w) << 16);
    *(uint2*)(hbf + i) = o;
  } else {
    int idx = bid - 16384;                 // 192 n-tiles x 128 k-tiles
    int n0 = (idx % 192) * 32, k0 = (idx / 192) * 32;
    int tx = t & 31, ty0 = t >> 5;
#pragma unroll
    for (int i = 0; i < 4; i++) {
      int ty = ty0 + i * 8;
      tile[ty][tx] = f2bf(wqkv[(size_t)(k0 + ty) * QKV_N + n0 + tx]);
    }
    __syncthreads();
#pragma unroll
    for (int i = 0; i < 4; i++) {
      int ty = ty0 + i * 8;
      wT[(size_t)(n0 + ty) * Hdim + k0 + tx] = tile[tx][ty];
    }
  }
}

// ---------------- k_mid: RoPE + V^T repack + wo transpose (merged, all post-GEMM1) ----
// RoPE writes qkv cols < 5120; vt reads cols >= 5120; woT touches wo/wT only -> disjoint.
// r15: sincosf -> __sincosf (fast-path v_sin/v_cos; RoPE was VALU-heavy with 10.5M libm
// sincos per launch; rotation is magnitude-preserving so bf16 accuracy is unaffected).
__global__ void k_mid(unsigned short* __restrict__ qkv, const int* __restrict__ pos,
                      unsigned short* __restrict__ vt,
                      const float* __restrict__ wo, unsigned short* __restrict__ wT) {
  __shared__ unsigned short tile[32][33];
  int bid = blockIdx.x;
  int t = threadIdx.x;
  if (bid < 40960) {
    int x = bid % 10;
    int bs = bid / 10;                     // b*S + s
    int head = x * 4 + (t >> 6);           // 0..39 (0-31 q, 32-39 k)
    int p = t & 63;                        // pair index
    int col;
    float scale;
    if (head < NH) { col = head * HDs + 2 * p; scale = SCALEF * LOG2E; }
    else           { col = NH * HDs + (head - NH) * HDs + 2 * p; scale = 1.f; }
    size_t idx = (size_t)bs * QKV_N + col;
    float x0 = bf2f(qkv[idx]), x1 = bf2f(qkv[idx + 1]);
    float position = (float)pos[bs];
    float inv_freq = exp2f((float)p * -0.2076205059304601f);
    float ang = position * inv_freq;
    float sv, cv;
    __sincosf(ang, &sv, &cv);
    qkv[idx]     = f2bf((x0 * cv - x1 * sv) * scale);
    qkv[idx + 1] = f2bf((x1 * cv + x0 * sv) * scale);
  } else if (bid < 45056) {
    int idx = bid - 40960;
    int bkv = idx >> 8;                    // b*NKV + kvh
    int d0 = ((idx >> 6) & 3) * 32;
    int s0 = (idx & 63) * 32;
    int b = bkv >> 3, kvh = bkv & 7;
    int tx = t & 31, ty0 = t >> 5;
    const unsigned short* src = qkv + (size_t)b * Ss * QKV_N + NH * HDs + NKV * HDs + kvh * HDs;
#pragma unroll
    for (int i = 0; i < 4; i++) {
      int ty = ty0 + i * 8;
      tile[ty][tx] = src[(size_t)(s0 + ty) * QKV_N + d0 + tx];
    }
    __syncthreads();
    unsigned short* dst = vt + (size_t)bkv * HDs * Ss;
    int c = s0 + tx;
    int o = c & 63;
    int pcol = (c & ~63) | ((o & 32) | ((o & 12) << 1) | ((o & 16) >> 2) | (o & 3));
#pragma unroll
    for (int i = 0; i < 4; i++) {
      int ty = ty0 + i * 8;
      dst[(size_t)(d0 + ty) * Ss + pcol] = tile[tx][ty];
    }
  } else {
    int idx = bid - 45056;                 // 128 x 128 tiles
    int n0 = (idx % 128) * 32, k0 = (idx / 128) * 32;
    int tx = t & 31, ty0 = t >> 5;
#pragma unroll
    for (int i = 0; i < 4; i++) {
      int ty = ty0 + i * 8;
      tile[ty][tx] = f2bf(wo[(size_t)(k0 + ty) * Hdim + n0 + tx]);
    }
    __syncthreads();
#pragma unroll
    for (int i = 0; i < 4; i++) {
      int ty = ty0 + i * 8;
      wT[(size_t)(n0 + ty) * Hdim + k0 + tx] = tile[tx][ty];
    }
  }
}

// ---------------- bf16 GEMM, r7/r13 structure (plateau best: 37% MfmaUtil, 841 TF) -----
// BM=256, BN=128, BK=64, 512 thr (8 waves, 4M x 2N, 64x64/wave), 3-deep K-tile LDS
// rotation (144 KB), counted vmcnt(6) once per K-tile, 16x16x32 MFMA.  Six structures
// tested (r2/r7/r8/r9/r10/r14-32x32) land 29-37%; this is the measured best.  r14's
// 32x32 shape reintroduced bank conflicts (2.5e7) and lost 9% -- reverted.
template <int OUT_BF16>
__global__ __launch_bounds__(512) void k_gemm8(const unsigned short* __restrict__ A,
                                               const unsigned short* __restrict__ Bt,
                                               void* __restrict__ C,
                                               int M, int N, int K, int nbn) {
  __shared__ __align__(16) unsigned short As[3][256 * 64];   // 96 KB
  __shared__ __align__(16) unsigned short Bs[3][128 * 64];   // 48 KB

  int nwg = gridDim.x;
  int orig = blockIdx.x;
  int wg = (orig & 7) * (nwg >> 3) + (orig >> 3);
  int bm = wg / nbn, bn = wg % nbn;

  int t = threadIdx.x, w = t >> 6, lane = t & 63;
  int wm = w >> 1, wn = w & 1;
  int l15 = lane & 15, l4 = lane >> 4;

  const unsigned short* Ag = A + (size_t)(bm * 256) * K;
  const unsigned short* Bg = Bt + (size_t)(bn * 128) * K;

  int srow = w * 8 + (lane >> 3);
  int sloff = ((lane & 7) ^ ((lane >> 3) & 7)) * 8;

  f32x4 zero = {0.f, 0.f, 0.f, 0.f};
  f32x4 acc[4][4];
#pragma unroll
  for (int m = 0; m < 4; m++)
#pragma unroll
    for (int n = 0; n < 4; n++) acc[m][n] = zero;

  int NKT = K >> 6;

  auto stage_half = [&](int buf, int kt, int h) {
#pragma unroll
    for (int i2 = 0; i2 < 2; i2++) {
      int row = h * 128 + i2 * 64 + srow;
      __builtin_amdgcn_global_load_lds(GLOBAL_AS(Ag + (size_t)row * K + kt * 64 + sloff),
                                       LDS_AS(&As[buf][h * 8192 + i2 * 4096 + w * 512]), 16, 0, 0);
    }
    {
      int row = h * 64 + srow;
      __builtin_amdgcn_global_load_lds(GLOBAL_AS(Bg + (size_t)row * K + kt * 64 + sloff),
                                       LDS_AS(&Bs[buf][h * 4096 + w * 512]), 16, 0, 0);
    }
  };

  stage_half(0, 0, 0); stage_half(0, 0, 1);
  stage_half(1, 1, 0); stage_half(1, 1, 1);
  asm volatile("s_waitcnt vmcnt(6)" ::: "memory");
  __builtin_amdgcn_s_barrier();

  for (int kt = 0; kt < NKT; kt++) {
    int cb = kt % 3;
    const unsigned short* Abp = As[cb];
    const unsigned short* Bbp = Bs[cb];
#pragma unroll
    for (int q = 0; q < 2; q++) {
      bf16x8 af[4], bf[4];
#pragma unroll
      for (int m = 0; m < 4; m++) {
        int row = wm * 64 + m * 16 + l15;
        int ph = (q * 4 + l4) ^ (row & 7);
        af[m] = *(const bf16x8*)&Abp[row * 64 + ph * 8];
      }
#pragma unroll
      for (int n = 0; n < 4; n++) {
        int row = wn * 64 + n * 16 + l15;
        int ph = (q * 4 + l4) ^ (row & 7);
        bf[n] = *(const bf16x8*)&Bbp[row * 64 + ph * 8];
      }
      if (kt + 2 < NKT) stage_half((kt + 2) % 3, kt + 2, q);
      __builtin_amdgcn_s_barrier();
      asm volatile("s_waitcnt lgkmcnt(0)" ::: "memory");
      __builtin_amdgcn_s_setprio(1);
#pragma unroll
      for (int m = 0; m < 4; m++)
#pragma unroll
        for (int n = 0; n < 4; n++)
          acc[m][n] = __builtin_amdgcn_mfma_f32_16x16x32_bf16(af[m], bf[n], acc[m][n], 0, 0, 0);
      __builtin_amdgcn_s_setprio(0);
      if (q == 1) {
        if (kt + 2 < NKT) asm volatile("s_waitcnt vmcnt(6)" ::: "memory");
        else              asm volatile("s_waitcnt vmcnt(0)" ::: "memory");
      }
      __builtin_amdgcn_s_barrier();
    }
  }

#pragma unroll
  for (int m = 0; m < 4; m++)
#pragma unroll
    for (int n = 0; n < 4; n++) {
      int col = bn * 128 + wn * 64 + n * 16 + l15;
#pragma unroll
      for (int r = 0; r < 4; r++) {
        int row = bm * 256 + wm * 64 + m * 16 + l4 * 4 + r;
        float v = acc[m][n][r];
        if (OUT_BF16)
          ((unsigned short*)C)[(size_t)row * N + col] = f2bf(v);
        else
          ((float*)C)[(size_t)row * N + col] = v;
      }
    }
}

// ---------------- Flash attention v5b (r12/r13, unchanged): 8 waves, true LPT ----------
__global__ __launch_bounds__(512, 4) void k_attn(const unsigned short* __restrict__ qkv,
                                                 const unsigned short* __restrict__ vt,
                                                 unsigned short* __restrict__ out) {
  __shared__ __align__(16) unsigned short Ks[2][64 * 128];   // 32 KB
  __shared__ __align__(16) unsigned short Vs[2][128 * 64];   // 32 KB

  int bid = blockIdx.x;
  int qc = 15 - (bid >> 6);     // true LPT: heavy q-chunks dispatched first
  int bh = bid & 63;
  int h = bh & 31;
  int b = bh >> 5;
  int kvh = h >> 2;             // GROUP = 4
  int t = threadIdx.x;
  int w = t >> 6, lane = t & 63;
  int l15 = lane & 15, l4 = lane >> 4;
  int qb0 = qc * 128;
  int qw = qb0 + w * 16;        // this wave's 16 q rows

  const unsigned short* kbase = qkv + (size_t)b * Ss * QKV_N + NH * HDs + (size_t)kvh * HDs;
  const unsigned short* vbase = vt + ((size_t)(b * NKV + kvh)) * HDs * Ss;

  bf16x8 qf[4];
#pragma unroll
  for (int ch = 0; ch < 4; ch++)
    qf[ch] = *(const bf16x8*)&qkv[((size_t)(b * Ss) + qw + l15) * QKV_N +
                                  (size_t)h * HDs + ch * 32 + l4 * 8];

  f32x4 zero = {0.f, 0.f, 0.f, 0.f};
  f32x4 acc[8];
#pragma unroll
  for (int dt = 0; dt < 8; dt++) acc[dt] = zero;
  float mrun = -1e30f, lsum = 0.f;

  int nkv = qc * 2 + 2;

  auto stageK = [&](int bufi, int kv_) {
#pragma unroll
    for (int i2 = 0; i2 < 2; i2++) {
      int row = i2 * 32 + (t >> 4);
      int sl = (t & 15) ^ (row & 7);
      __builtin_amdgcn_global_load_lds(GLOBAL_AS(kbase + (size_t)(kv_ + row) * QKV_N + sl * 8),
                                       LDS_AS(&Ks[bufi][i2 * 4096 + w * 512]), 16, 0, 0);
    }
  };
  auto stageV = [&](int bufi, int kv_) {
#pragma unroll
    for (int i2 = 0; i2 < 2; i2++) {
      int row = i2 * 64 + (t >> 3);
      int sl = (t & 7) ^ (row & 7);
      __builtin_amdgcn_global_load_lds(GLOBAL_AS(vbase + (size_t)row * Ss + kv_ + sl * 8),
                                       LDS_AS(&Vs[bufi][i2 * 4096 + w * 512]), 16, 0, 0);
    }
  };

  stageK(0, 0); stageV(0, 0);
  for (int it = 0; it < nkv; it++) {
    int kvb = it * 64;
    bool more = (it + 1 < nkv);
    if (more) {
      stageK((it + 1) & 1, kvb + 64);
      stageV((it + 1) & 1, kvb + 64);
      asm volatile("s_waitcnt vmcnt(4)" ::: "memory");
    } else {
      asm volatile("s_waitcnt vmcnt(0)" ::: "memory");
    }
    __builtin_amdgcn_s_barrier();

    if (kvb <= qw + 15) {
      const unsigned short* Kb = Ks[it & 1];
      const unsigned short* Vb = Vs[it & 1];

      f32x4 sacc[4];
#pragma unroll
      for (int kt2 = 0; kt2 < 4; kt2++) sacc[kt2] = zero;
#pragma unroll
      for (int kt2 = 0; kt2 < 4; kt2++) {
        int row = kt2 * 16 + l15;
#pragma unroll
        for (int ch = 0; ch < 4; ch++) {
          int ps = (ch * 4 + l4) ^ (row & 7);
          bf16x8 kf = *(const bf16x8*)&Kb[row * 128 + ps * 8];
          sacc[kt2] = __builtin_amdgcn_mfma_f32_16x16x32_bf16(kf, qf[ch], sacc[kt2], 0, 0, 0);
        }
      }

      int qi = qw + l15;
      bool fullvis = (kvb + 63 <= qw);
      float pv[16];
      float tmax = -1e30f;
#pragma unroll
      for (int kt2 = 0; kt2 < 4; kt2++)
#pragma unroll
        for (int r = 0; r < 4; r++) {
          int kvi = kvb + kt2 * 16 + l4 * 4 + r;
          float v = sacc[kt2][r];
          if (!fullvis) v = (kvi <= qi) ? v : -1e30f;
          pv[kt2 * 4 + r] = v;
          tmax = fmaxf(tmax, v);
        }
      tmax = fmaxf(tmax, __shfl_xor(tmax, 16));
      tmax = fmaxf(tmax, __shfl_xor(tmax, 32));
      if (!__all(tmax - mrun <= 8.f)) {
        float mnew = fmaxf(mrun, tmax);
        float fsc = exp2f(mrun - mnew);
        mrun = mnew;
        lsum *= fsc;
        float fr[4];
#pragma unroll
        for (int r = 0; r < 4; r++) fr[r] = __shfl(fsc, l4 * 4 + r);
#pragma unroll
        for (int dt = 0; dt < 8; dt++)
#pragma unroll
        for (int r = 0; r < 4; r++) acc[dt][r] *= fr[r];
      }
      float rs = 0.f;
#pragma unroll
      for (int i = 0; i < 16; i++) {
        pv[i] = exp2f(pv[i] - mrun);
        rs += pv[i];
      }
      rs += __shfl_xor(rs, 16);
      rs += __shfl_xor(rs, 32);
      lsum += rs;

      bf16x8 pa[2];
      {
        union { unsigned u[4]; bf16x8 v8; } pk0, pk1;
#pragma unroll
        for (int i = 0; i < 4; i++) pk0.u[i] = cvtpk(pv[2 * i], pv[2 * i + 1]);
#pragma unroll
        for (int i = 0; i < 4; i++) pk1.u[i] = cvtpk(pv[8 + 2 * i], pv[8 + 2 * i + 1]);
        pa[0] = pk0.v8;
        pa[1] = pk1.v8;
      }

#pragma unroll
      for (int kc = 0; kc < 2; kc++)
#pragma unroll
        for (int dt = 0; dt < 8; dt++) {
          int d = dt * 16 + l15;
          int ps = (kc * 4 + l4) ^ (d & 7);
          bf16x8 vf = *(const bf16x8*)&Vb[d * 64 + ps * 8];
          acc[dt] = __builtin_amdgcn_mfma_f32_16x16x32_bf16(pa[kc], vf, acc[dt], 0, 0, 0);
        }
    }
    asm volatile("s_waitcnt lgkmcnt(0)" ::: "memory");
    __builtin_amdgcn_s_barrier();
  }

  float lr[4];
#pragma unroll
  for (int r = 0; r < 4; r++) lr[r] = __shfl(lsum, l4 * 4 + r);
#pragma unroll
  for (int dt = 0; dt < 8; dt++)
#pragma unroll
    for (int r = 0; r < 4; r++) {
      int row = qw + l4 * 4 + r;
      out[((size_t)(b * Ss) + row) * Hdim + (size_t)h * HDs + dt * 16 + l15] =
          f2bf(acc[dt][r] / lr[r]);
    }
}

// ---------------- launcher ----------------
extern "C" void kernel_launch(void* const* d_in, const int* in_sizes, int n_in,
                              void* d_out, int out_size, void* d_ws, size_t ws_size,
                              hipStream_t stream) {
  const float* hidden = (const float*)d_in[0];
  const int* positions = (const int*)d_in[1];
  const float* wqkv = (const float*)d_in[2];
  const float* wo = (const float*)d_in[3];
  float* out = (float*)d_out;
  char* ws = (char*)d_ws;

  unsigned short* hbf  = (unsigned short*)(ws);
  unsigned short* wT   = (unsigned short*)(ws + 33554432);
  unsigned short* qkvb = (unsigned short*)(ws + 83886080);
  unsigned short* vtb  = (unsigned short*)(ws + 134217728);

  // 1. pre: hidden fp32->bf16 + wqkvT  (merged: 16384 + 24576 blocks)
  k_pre<<<40960, 256, 0, stream>>>(hidden, hbf, wqkv, wT);
  // 2. qkv = hidden @ wqkv   (bf16 out), grid 16x48 = 768 (%8==0)
  k_gemm8<1><<<(4096 / 256) * (QKV_N / 128), 512, 0, stream>>>(hbf, wT, qkvb, 4096, QKV_N, 4096, QKV_N / 128);
  // 3. mid: RoPE + V^T repack + woT  (merged: 40960 + 4096 + 16384 blocks)
  k_mid<<<61440, 256, 0, stream>>>(qkvb, positions, vtb, wo, wT);
  // 4. flash attention v5b -> attn_out (reuses ws0)
  k_attn<<<Bb * NH * (Ss / 128), 512, 0, stream>>>(qkvb, vtb, hbf);
  // 5. out = attn_out @ wo  (fp32 out), grid 16x32 = 512 (%8==0)
  k_gemm8<0><<<(4096 / 256) * (4096 / 128), 512, 0, stream>>>(hbf, wT, out, 4096, 4096, 4096, 4096 / 128);
}